// Round 16
// baseline (75.800 us; speedup 1.0000x reference)
//
#include <hip/hip_runtime.h>
#include <hip/hip_cooperative_groups.h>
#include <hip/hip_bf16.h>
#include <math.h>

namespace cg = cooperative_groups;

#define B_   16
#define N_   32
#define I_   1152
#define DIN  16
#define D_   64
#define JC   16            // i-chunks (coop)
#define IPC  72            // i's per coop block
#define TI   16            // i's per k_xhat block (fallback)
#define IB   (I_/TI)       // 72
#define IC   16            // i-chunks in fallback routing
#define BND  (B_*N_*D_)    // 32768

#if __has_builtin(__builtin_amdgcn_exp2f)
#define EXP2(x) __builtin_amdgcn_exp2f(x)
#else
#define EXP2(x) exp2f(x)
#endif

#define LOG2E 1.4426950408889634f

typedef __attribute__((ext_vector_type(8))) short short8v;
typedef __attribute__((ext_vector_type(4))) float f32x4;
typedef __attribute__((ext_vector_type(4))) unsigned int u32x4;
typedef __attribute__((ext_vector_type(2))) unsigned int u32x2;

__device__ __forceinline__ float squash1(float s) {
    float sq = s * s;
    return (sq / (1.0f + sq)) * s * rsqrtf(sq + 1e-9f);
}
__device__ __forceinline__ unsigned int bfh(float v) {
    return (unsigned int)__builtin_bit_cast(unsigned short, __float2bfloat16(v));
}
__device__ __forceinline__ float bff(unsigned int hi16) {
    return __builtin_bit_cast(float, hi16 << 16);
}
__device__ __forceinline__ unsigned int cvtpk(float a, float b) {
    unsigned int r;
    asm("v_cvt_pk_bf16_f32 %0, %1, %2" : "=v"(r) : "v"(a), "v"(b));
    return r;
}

// ================= cooperative path (x_hat register-resident) ===============
// 512 blocks (n x 16 chunks) x 256 thr; wave = d m-tile owning all 72 i's.
// x_hat in pk[144] (bf16 pairs); W streamed once; grid.sync between phases.
// Launch is guarded host-side by an occupancy query + error check; if the
// runtime can't co-schedule 2 blocks/CU we fall back to the R13 pipeline.
__global__ __launch_bounds__(256, 2) void k_caps(const float* __restrict__ inp,
                                                 const float* __restrict__ W,
                                                 float* __restrict__ outp,
                                                 float* __restrict__ p0,
                                                 float* __restrict__ za1,
                                                 float* __restrict__ za2) {
    __shared__ __align__(16) unsigned short xs[IPC * 256];  // [il][ko][b][8] bf16 (36KB)

    cg::grid_group grid = cg::this_grid();

    const int bid = blockIdx.x;
    const int n  = bid >> 4;
    const int jc = bid & 15;
    const int t  = threadIdx.x;
    const int l  = t & 63;
    const int w  = t >> 6;                 // wave = d m-tile 0..3
    const int b  = l & 15;
    const int dg = l >> 4;
    const int ko = dg & 1;
    const bool loHalf = (l >= 32);
    const int d0 = w * 16 + dg * 4;

    for (int rep = 0; rep < 5; ++rep) {
        int slot = rep * 256 + t;
        if (slot < IPC * 16) {
            int il = slot >> 4, bb = slot & 15;
            const float* src = inp + (size_t)bb * (I_ * DIN) + (size_t)(jc * IPC + il) * DIN;
            f32x4 a0 = *(const f32x4*)src;
            f32x4 a1 = *(const f32x4*)(src + 4);
            f32x4 a2 = *(const f32x4*)(src + 8);
            f32x4 a3 = *(const f32x4*)(src + 12);
            u32x4 q0, q1;
            q0.x = (bfh(a0.y) << 16) | bfh(a0.x);
            q0.y = (bfh(a0.w) << 16) | bfh(a0.z);
            q0.z = (bfh(a1.y) << 16) | bfh(a1.x);
            q0.w = (bfh(a1.w) << 16) | bfh(a1.z);
            q1.x = (bfh(a2.y) << 16) | bfh(a2.x);
            q1.y = (bfh(a2.w) << 16) | bfh(a2.z);
            q1.z = (bfh(a3.y) << 16) | bfh(a3.x);
            q1.w = (bfh(a3.w) << 16) | bfh(a3.z);
            *(u32x4*)(xs + il * 256 + bb * 8)       = q0;
            *(u32x4*)(xs + il * 256 + 128 + bb * 8) = q1;
        }
    }
    __syncthreads();

    const float* wb = W + ((size_t)(n * I_ + jc * IPC) * D_ + w * 16 + b) * DIN + ko * 8;

    unsigned int pk[IPC * 2];
    f32x4 s0v = {0.f, 0.f, 0.f, 0.f};

    #pragma unroll
    for (int c = 0; c < IPC / 4; ++c) {
        f32x4 wv[8];
        #pragma unroll
        for (int j = 0; j < 4; ++j) {
            const f32x4* p = (const f32x4*)(wb + (size_t)(c * 4 + j) * 1024);
            wv[2 * j] = p[0]; wv[2 * j + 1] = p[1];
        }
        #pragma unroll
        for (int j = 0; j < 4; ++j) {
            const int i = c * 4 + j;
            short8v bfrag = *(const short8v*)(xs + i * 256 + ko * 128 + b * 8);
            short8v afrag;
            #pragma unroll
            for (int q = 0; q < 8; ++q) {
                float wq = wv[2 * j + (q >> 2)][q & 3];
                unsigned int hi = bfh(wq);
                unsigned int lo = bfh(wq - bff(hi));
                afrag[q] = (short)(loHalf ? lo : hi);
            }
            f32x4 acc = __builtin_amdgcn_mfma_f32_16x16x32_bf16(
                afrag, bfrag, (f32x4){0.f, 0.f, 0.f, 0.f}, 0, 0, 0);
            s0v += acc;
            pk[i * 2]     = (bfh(acc[1]) << 16) | bfh(acc[0]);
            pk[i * 2 + 1] = (bfh(acc[3]) << 16) | bfh(acc[2]);
        }
    }

    *(f32x4*)(p0 + (size_t)(n * JC + jc) * 1024 + b * 64 + d0) = s0v;
    __threadfence();
    grid.sync();

#define ROUTE_PASS(C2, ZZ, AA)                                                  \
    _Pragma("unroll")                                                           \
    for (int iw = 0; iw < IPC; ++iw) {                                          \
        unsigned int u0 = pk[iw * 2], u1 = pk[iw * 2 + 1];                      \
        float x0 = __builtin_bit_cast(float, u0 << 16);                         \
        float x1 = __builtin_bit_cast(float, u0 & 0xffff0000u);                 \
        float x2 = __builtin_bit_cast(float, u1 << 16);                         \
        float x3 = __builtin_bit_cast(float, u1 & 0xffff0000u);                 \
        float e0 = EXP2(x0 * C2[0]); ZZ[0] += e0; AA[0] = fmaf(e0, x0, AA[0]);  \
        float e1 = EXP2(x1 * C2[1]); ZZ[1] += e1; AA[1] = fmaf(e1, x1, AA[1]);  \
        float e2 = EXP2(x2 * C2[2]); ZZ[2] += e2; AA[2] = fmaf(e2, x2, AA[2]);  \
        float e3 = EXP2(x3 * C2[3]); ZZ[3] += e3; AA[3] = fmaf(e3, x3, AA[3]);  \
    }

    float coef0[4], c2[4];
    {
        f32x4 s = {0.f, 0.f, 0.f, 0.f};
        #pragma unroll
        for (int j = 0; j < JC; ++j)
            s += *(const f32x4*)(p0 + (size_t)(n * JC + j) * 1024 + b * 64 + d0);
        #pragma unroll
        for (int r = 0; r < 4; ++r) {
            coef0[r] = squash1(s[r] * (1.0f / (float)I_));
            c2[r] = coef0[r] * LOG2E;
        }
    }
    float z[4] = {0, 0, 0, 0}, a[4] = {0, 0, 0, 0};
    ROUTE_PASS(c2, z, a)
    {
        size_t base = ((size_t)(n * JC + jc) * 1024 + b * 64 + d0) * 2;
        *(f32x4*)(za1 + base)     = (f32x4){z[0], a[0], z[1], a[1]};
        *(f32x4*)(za1 + base + 4) = (f32x4){z[2], a[2], z[3], a[3]};
    }
    __threadfence();
    grid.sync();

    float cn2[4];
    {
        f32x4 Z = {0.f, 0.f, 0.f, 0.f}, A = {0.f, 0.f, 0.f, 0.f};
        #pragma unroll
        for (int j = 0; j < JC; ++j) {
            size_t base = ((size_t)(n * JC + j) * 1024 + b * 64 + d0) * 2;
            f32x4 v0 = *(const f32x4*)(za1 + base);
            f32x4 v1 = *(const f32x4*)(za1 + base + 4);
            Z += (f32x4){v0[0], v0[2], v1[0], v1[2]};
            A += (f32x4){v0[1], v0[3], v1[1], v1[3]};
        }
        #pragma unroll
        for (int r = 0; r < 4; ++r)
            cn2[r] = (coef0[r] + squash1(A[r] / Z[r])) * LOG2E;
    }
    float z2[4] = {0, 0, 0, 0}, a2[4] = {0, 0, 0, 0};
    ROUTE_PASS(cn2, z2, a2)
    {
        size_t base = ((size_t)(n * JC + jc) * 1024 + b * 64 + d0) * 2;
        *(f32x4*)(za2 + base)     = (f32x4){z2[0], a2[0], z2[1], a2[1]};
        *(f32x4*)(za2 + base + 4) = (f32x4){z2[2], a2[2], z2[3], a2[3]};
    }
    __threadfence();
    grid.sync();

    if (jc == 0) {
        f32x4 Z = {0.f, 0.f, 0.f, 0.f}, A = {0.f, 0.f, 0.f, 0.f};
        #pragma unroll
        for (int j = 0; j < JC; ++j) {
            size_t base = ((size_t)(n * JC + j) * 1024 + b * 64 + d0) * 2;
            f32x4 v0 = *(const f32x4*)(za2 + base);
            f32x4 v1 = *(const f32x4*)(za2 + base + 4);
            Z += (f32x4){v0[0], v0[2], v1[0], v1[2]};
            A += (f32x4){v0[1], v0[3], v1[1], v1[3]};
        }
        f32x4 o;
        #pragma unroll
        for (int r = 0; r < 4; ++r) o[r] = squash1(A[r] / Z[r]);
        *(f32x4*)(outp + (size_t)b * (N_ * D_) + n * 64 + d0) = o;
    }
#undef ROUTE_PASS
}

// ===================== fallback path (R13, 75.8us, validated) ===============
__global__ __launch_bounds__(256, 3) void k_xhat(const float* __restrict__ inp,
                                                 const float* __restrict__ W,
                                                 unsigned short* __restrict__ xh2,
                                                 float* __restrict__ part) {
    __shared__ __align__(16) unsigned short xs[4096];
    const int bx = blockIdx.x;
    const int n  = bx / IB;
    const int ib = bx % IB;
    const int i0 = ib * TI;
    const int t  = threadIdx.x;
    const int l  = t & 63;
    const int mt = t >> 6;
    const int row = l & 15;
    const int ko  = (l >> 4) & 1;
    const bool loHalf = (l >= 32);

    #pragma unroll
    for (int rep = 0; rep < 2; ++rep) {
        int s   = rep * 256 + t;
        int bb  = s >> 5;
        int il  = (s >> 1) & 15;
        int sko = s & 1;
        const float* src = inp + (size_t)bb * (I_ * DIN) + (size_t)(i0 + il) * DIN + sko * 8;
        f32x4 a0 = *(const f32x4*)src;
        f32x4 a1 = *(const f32x4*)(src + 4);
        u32x4 p;
        p.x = cvtpk(a0.x, a0.y);
        p.y = cvtpk(a0.z, a0.w);
        p.z = cvtpk(a1.x, a1.y);
        p.w = cvtpk(a1.z, a1.w);
        int base = (bb * 512 + il * 32 + sko * 16) ^ ((bb & 7) << 4);
        *(u32x4*)((char*)xs + base) = p;
    }
    __syncthreads();

    const float* wb = W + ((size_t)(n * I_ + i0) * 64 + mt * 16 + row) * 16 + ko * 8;

    unsigned int pk[TI * 2];
    f32x4 s0v = {0.f, 0.f, 0.f, 0.f};

#define LOADG(DST, C) {                                                        \
        _Pragma("unroll")                                                      \
        for (int j = 0; j < 4; ++j) {                                          \
            const f32x4* p = (const f32x4*)(wb + (size_t)((C) * 4 + j) * 1024);\
            DST[2 * j] = p[0]; DST[2 * j + 1] = p[1];                          \
        } }

#define COMPG(SRC, C) {                                                        \
        _Pragma("unroll")                                                      \
        for (int j = 0; j < 4; ++j) {                                          \
            const int i = (C) * 4 + j;                                         \
            f32x4 w0 = SRC[2 * j], w1 = SRC[2 * j + 1];                        \
            u32x4 b0 = __builtin_bit_cast(u32x4, w0);                          \
            u32x4 b1 = __builtin_bit_cast(u32x4, w1);                          \
            u32x4 ah, al;                                                      \
            ah.x = __builtin_amdgcn_perm(b0.y, b0.x, 0x07060302u);             \
            ah.y = __builtin_amdgcn_perm(b0.w, b0.z, 0x07060302u);             \
            ah.z = __builtin_amdgcn_perm(b1.y, b1.x, 0x07060302u);             \
            ah.w = __builtin_amdgcn_perm(b1.w, b1.z, 0x07060302u);             \
            float r0 = w0.x - __builtin_bit_cast(float, b0.x & 0xffff0000u);   \
            float r1 = w0.y - __builtin_bit_cast(float, b0.y & 0xffff0000u);   \
            float r2 = w0.z - __builtin_bit_cast(float, b0.z & 0xffff0000u);   \
            float r3 = w0.w - __builtin_bit_cast(float, b0.w & 0xffff0000u);   \
            float r4 = w1.x - __builtin_bit_cast(float, b1.x & 0xffff0000u);   \
            float r5 = w1.y - __builtin_bit_cast(float, b1.y & 0xffff0000u);   \
            float r6 = w1.z - __builtin_bit_cast(float, b1.z & 0xffff0000u);   \
            float r7 = w1.w - __builtin_bit_cast(float, b1.w & 0xffff0000u);   \
            al.x = cvtpk(r0, r1);                                              \
            al.y = cvtpk(r2, r3);                                              \
            al.z = cvtpk(r4, r5);                                              \
            al.w = cvtpk(r6, r7);                                              \
            u32x4 aw;                                                          \
            aw.x = loHalf ? al.x : ah.x;                                       \
            aw.y = loHalf ? al.y : ah.y;                                       \
            aw.z = loHalf ? al.z : ah.z;                                       \
            aw.w = loHalf ? al.w : ah.w;                                       \
            short8v afrag = __builtin_bit_cast(short8v, aw);                   \
            int xaddr = ((l & 15) * 512 + i * 32 + ko * 16) ^ (((l & 15) & 7) << 4); \
            short8v bfrag = *(const short8v*)((const char*)xs + xaddr);        \
            f32x4 acc = __builtin_amdgcn_mfma_f32_16x16x32_bf16(               \
                afrag, bfrag, (f32x4){0.f, 0.f, 0.f, 0.f}, 0, 0, 0);           \
            s0v += acc;                                                        \
            pk[i * 2]     = cvtpk(acc[0], acc[1]);                             \
            pk[i * 2 + 1] = cvtpk(acc[2], acc[3]);                             \
        } }

    f32x4 wA[8], wB[8];
    LOADG(wA, 0)
    LOADG(wB, 1)
    COMPG(wA, 0)
    LOADG(wA, 2)
    COMPG(wB, 1)
    LOADG(wB, 3)
    COMPG(wA, 2)
    COMPG(wB, 3)
#undef LOADG
#undef COMPG

    size_t pidx = (((size_t)ib * B_ + (l & 15)) * N_ + n) * 64 + mt * 16 + (l >> 4) * 4;
    *(f32x4*)(part + pidx) = s0v;

    #pragma unroll
    for (int i = 0; i < TI; ++i) {
        u32x2 v;
        v.x = pk[i * 2];
        v.y = pk[i * 2 + 1];
        size_t off = (size_t)(n * I_ + i0 + i) * 1024 + (size_t)t * 4;
        *reinterpret_cast<u32x2*>(xh2 + off) = v;
    }
}

__global__ __launch_bounds__(256) void k_out0(const float* __restrict__ part,
                                              float* __restrict__ coef) {
    const int t = blockIdx.x * 256 + threadIdx.x;
    float s = 0.0f;
    for (int j = 0; j < IB; ++j) s += part[(size_t)j * BND + t];
    s *= (1.0f / (float)I_);
    coef[t] = squash1(s);
}

__global__ __launch_bounds__(256) void k_rpart(const unsigned short* __restrict__ xh2,
                                               const float* __restrict__ coef,
                                               float* __restrict__ part2) {
    const int bx = blockIdx.x;
    const int n  = bx >> 4;
    const int ic = bx & 15;
    const int t  = threadIdx.x;
    const int b  = t & 15;
    const int d0 = (t >> 4) * 4;

    const unsigned short* base = xh2 + ((size_t)n * I_ + (size_t)ic * (I_ / IC)) * 1024
                               + (size_t)t * 4;
    f32x4 c4 = *(const f32x4*)(coef + ((size_t)b * N_ + n) * 64 + d0);
    float c2[4] = {c4.x * LOG2E, c4.y * LOG2E, c4.z * LOG2E, c4.w * LOG2E};
    float z[4] = {0, 0, 0, 0}, a[4] = {0, 0, 0, 0};

    #pragma unroll 8
    for (int i = 0; i < I_ / IC; ++i) {
        u32x2 u = *(const u32x2*)(base + (size_t)i * 1024);
        unsigned short s4[4] = {(unsigned short)(u.x & 0xffffu), (unsigned short)(u.x >> 16),
                                (unsigned short)(u.y & 0xffffu), (unsigned short)(u.y >> 16)};
        #pragma unroll
        for (int j = 0; j < 4; ++j) {
            float x = bff(s4[j]);
            float e = EXP2(x * c2[j]);
            z[j] += e;
            a[j] = fmaf(e, x, a[j]);
        }
    }

    size_t pidx = ((((size_t)ic * N_ + n) * 16 + b) * 64 + d0) * 2;
    f32x4 v0 = {z[0], a[0], z[1], a[1]};
    f32x4 v1 = {z[2], a[2], z[3], a[3]};
    *(f32x4*)(part2 + pidx)     = v0;
    *(f32x4*)(part2 + pidx + 4) = v1;
}

__global__ __launch_bounds__(256) void k_rfin(const float* __restrict__ part2,
                                              const float* __restrict__ coefIn,
                                              float* __restrict__ outp,
                                              int final_) {
    const int gid = blockIdx.x * 256 + threadIdx.x;
    float Z = 0.0f, A = 0.0f;
    #pragma unroll
    for (int ic = 0; ic < IC; ++ic) {
        const float* p = part2 + ((size_t)ic * BND + gid) * 2;
        Z += p[0];
        A += p[1];
    }
    const int d = gid & 63, b = (gid >> 6) & 15, n = gid >> 10;
    const int ci = (b * N_ + n) * D_ + d;
    float o = squash1(A / Z);
    outp[ci] = final_ ? o : (coefIn[ci] + o);
}

extern "C" void kernel_launch(void* const* d_in, const int* in_sizes, int n_in,
                              void* d_out, int out_size, void* d_ws, size_t ws_size,
                              hipStream_t stream) {
    const float* inp = (const float*)d_in[0];
    const float* W   = (const float*)d_in[1];
    float* out = (float*)d_out;

    // coop-path workspace (small, at head of ws)
    float* p0  = (float*)d_ws;                          // 32*16*1024 f32   = 2 MB
    float* za1 = (float*)((char*)d_ws + (2u << 20));    // 4 MB
    float* za2 = (float*)((char*)d_ws + (6u << 20));    // 4 MB

    // deterministic decision: can the coop grid (512 blocks) be co-resident?
    int occ = 0;
    hipError_t qe = hipOccupancyMaxActiveBlocksPerMultiprocessor(
        &occ, (const void*)k_caps, 256, 0);
    bool coop = (qe == hipSuccess && occ >= 2);

    if (coop) {
        void* args[] = {(void*)&inp, (void*)&W, (void*)&out,
                        (void*)&p0, (void*)&za1, (void*)&za2};
        hipError_t le = hipLaunchCooperativeKernel((void*)k_caps, dim3(N_ * JC),
                                                   dim3(256), args, 0, stream);
        if (le != hipSuccess) coop = false;
    }

    if (!coop) {
        // fallback = R13 pipeline (uses tail of ws; disjoint from coop buffers
        // is unnecessary since only one path runs, but keep layouts simple)
        unsigned short* xh2 = (unsigned short*)((char*)d_ws + (12u << 20));
        float* part  = (float*)((char*)d_ws + (12u << 20) + 75497472);
        float* part2 = (float*)((char*)d_ws + (12u << 20) + 84934656);
        float* coefb = (float*)((char*)d_ws + (12u << 20) + 89128960);

        k_xhat<<<dim3(N_ * IB), dim3(256), 0, stream>>>(inp, W, xh2, part);
        k_out0<<<dim3(BND / 256), dim3(256), 0, stream>>>(part, coefb);
        k_rpart<<<dim3(N_ * IC), dim3(256), 0, stream>>>(xh2, coefb, part2);
        k_rfin <<<dim3(BND / 256), dim3(256), 0, stream>>>(part2, coefb, coefb, 0);
        k_rpart<<<dim3(N_ * IC), dim3(256), 0, stream>>>(xh2, coefb, part2);
        k_rfin <<<dim3(BND / 256), dim3(256), 0, stream>>>(part2, coefb, out, 1);
    }
}